// Round 4
// baseline (466.616 us; speedup 1.0000x reference)
//
#include <hip/hip_runtime.h>

typedef _Float16 f16x8 __attribute__((ext_vector_type(8)));
typedef _Float16 f16x4 __attribute__((ext_vector_type(4)));
typedef float    f32x4 __attribute__((ext_vector_type(4)));

#define MROWS 16384
#define NCOLS 256
#define KDIM  4096
#define BM    32
#define BK    32
#define ITERS (KDIM / BK)   // 128
#define LDP   264           // P row stride (floats); 264%32==8 -> <=2-way on scalar writes

// out layout (floats): idx[32768] | scores[32768] | pf[1048576] | imp[64] | load[64]
#define OUT_SCORES 32768
#define OUT_PF     65536
#define OUT_IMP    1114112
#define OUT_LOAD   1114176

// ---------------- Kernel 1: W fp32 -> frag-major f16 hi/lo planes ----------------
// dst granule t (16B): l = t&63, NT = (t>>6)&15, ksg = t>>10
// covers element (n,k): n = NT*16 + (l&15), k = ksg*32 + (l>>4)*8 + j
__global__ __launch_bounds__(256) void wprep(const float* __restrict__ W,
                                             _Float16* __restrict__ wfHi,
                                             _Float16* __restrict__ wfLo) {
    int t   = blockIdx.x * 256 + threadIdx.x;   // 131072 granules
    int l   = t & 63;
    int NT  = (t >> 6) & 15;
    int ksg = t >> 10;
    int n   = NT * 16 + (l & 15);
    int k   = ksg * 32 + ((l >> 4) << 3);
    const float* src = W + ((size_t)n * KDIM + (size_t)k);
    f16x8 hi, lo;
#pragma unroll
    for (int j = 0; j < 8; ++j) {
        float x = src[j];
        _Float16 h = (_Float16)x;
        hi[j] = h;
        lo[j] = (_Float16)(x - (float)h);
    }
    *(f16x8*)(wfHi + (size_t)t * 8) = hi;
    *(f16x8*)(wfLo + (size_t)t * 8) = lo;
}

__device__ inline void cvt4(const f32x4 v, f16x4& hi, f16x4& lo) {
#pragma unroll
    for (int j = 0; j < 4; ++j) {
        _Float16 h = (_Float16)v[j];
        hi[j] = h;
        lo[j] = (_Float16)(v[j] - (float)h);
    }
}

// ---------------- Kernel 2: fused GEMM (3-pass f16 split) + softmax/top2/stats ----------------
// grid = 512 blocks x 256 threads (4 waves). Block owns 32 rows, full N=256.
// Wave w owns cols [w*64, w*64+64) == head w exactly.
// B(i+1) register-prefetched (MFMA never waits vmem); X prefetch distance 2.
__global__ __launch_bounds__(256, 2) void gemm_fused(const float* __restrict__ X,
        const _Float16* __restrict__ wfHi, const _Float16* __restrict__ wfLo,
        float* __restrict__ out) {
    __shared__ _Float16 aHi[2][BM * BK];   // frag-major, 2 KB per buf
    __shared__ _Float16 aLo[2][BM * BK];
    __shared__ float P[BM * LDP];          // per-head probs, 33.8 KB
    __shared__ float sImp[64], sLoad[64];

    const int tid  = threadIdx.x;
    const int lane = tid & 63;
    const int w    = tid >> 6;
    const int m0   = blockIdx.x * BM;

    f32x4 acc[2][4];
#pragma unroll
    for (int a = 0; a < 2; ++a)
#pragma unroll
        for (int b = 0; b < 4; ++b) acc[a][b] = (f32x4){0.f, 0.f, 0.f, 0.f};

    // staging: thread t -> granule g = t>>1 (8 f16), half h = t&1 (4 floats)
    const int g    = tid >> 1;
    const int h    = tid & 1;
    const int srow = ((g >> 6) << 4) + (g & 15);       // mi*16 + (lam&15)
    const int kst  = ((g >> 4) & 3) * 8 + h * 4;
    const float* xptr = X + ((size_t)(m0 + srow) * KDIM + kst);
    const int wo = g * 8 + h * 4;                      // f16 offset in plane

    // B frag pointers: granule = i*1024 + (w*4+ni)*64 + lane
    const _Float16* pBH = wfHi + ((size_t)w * 256 + (size_t)lane) * 8;
    const _Float16* pBL = wfLo + ((size_t)w * 256 + (size_t)lane) * 8;

    // ---- prologue ----
    {   // X(0) -> buf0 directly
        f32x4 v = *(const f32x4*)xptr;
        f16x4 hi, lo; cvt4(v, hi, lo);
        *(f16x4*)(&aHi[0][wo]) = hi;
        *(f16x4*)(&aLo[0][wo]) = lo;
    }
    f32x4 nxs0, nxs1;
    nxs1 = *(const f32x4*)(xptr + BK);                 // X(1) -> slot1
    nxs0 = nxs1;                                       // init (overwritten iter 0)
    f16x8 bHc[4], bLc[4];
#pragma unroll
    for (int ni = 0; ni < 4; ++ni) {
        bHc[ni] = *(const f16x8*)(pBH + ni * 512);
        bLc[ni] = *(const f16x8*)(pBL + ni * 512);
    }
    __syncthreads();

#pragma unroll 2
    for (int i = 0; i < ITERS; ++i) {
        const int cur = i & 1, nxt = cur ^ 1;

        // X(i+2) load into temp (assigned to slot i&1 at loop bottom)
        const int ipf = (i + 2 < ITERS) ? i + 2 : ITERS - 1;
        f32x4 xin = *(const f32x4*)(xptr + (size_t)ipf * BK);

        // B(i+1) prefetch
        const int ibn = (i + 1 < ITERS) ? i + 1 : i;
        const _Float16* nBH = pBH + (size_t)ibn * 8192;
        const _Float16* nBL = pBL + (size_t)ibn * 8192;
        f16x8 bHn[4], bLn[4];
#pragma unroll
        for (int ni = 0; ni < 4; ++ni) {
            bHn[ni] = *(const f16x8*)(nBH + ni * 512);
            bLn[ni] = *(const f16x8*)(nBL + ni * 512);
        }

        // MFMA block: A from LDS, B resident in registers
#pragma unroll
        for (int mi = 0; mi < 2; ++mi) {
            f16x8 aH = *(const f16x8*)(&aHi[cur][(mi * 64 + lane) * 8]);
            f16x8 aL = *(const f16x8*)(&aLo[cur][(mi * 64 + lane) * 8]);
#pragma unroll
            for (int ni = 0; ni < 4; ++ni) {
                acc[mi][ni] = __builtin_amdgcn_mfma_f32_16x16x32_f16(aH, bHc[ni], acc[mi][ni], 0, 0, 0);
                acc[mi][ni] = __builtin_amdgcn_mfma_f32_16x16x32_f16(aH, bLc[ni], acc[mi][ni], 0, 0, 0);
                acc[mi][ni] = __builtin_amdgcn_mfma_f32_16x16x32_f16(aL, bHc[ni], acc[mi][ni], 0, 0, 0);
            }
        }

        // convert X(i+1) (loaded 2 iters of latency ago) -> buf nxt
        if (i + 1 < ITERS) {
            f32x4 xv = ((i & 1) == 0) ? nxs1 : nxs0;   // slot (i+1)&1
            f16x4 hi, lo; cvt4(xv, hi, lo);
            *(f16x4*)(&aHi[nxt][wo]) = hi;
            *(f16x4*)(&aLo[nxt][wo]) = lo;
        }
        if ((i & 1) == 0) nxs0 = xin; else nxs1 = xin; // store X(i+2) in slot i&1
#pragma unroll
        for (int ni = 0; ni < 4; ++ni) { bHc[ni] = bHn[ni]; bLc[ni] = bLn[ni]; }
        __syncthreads();
    }

    // ================= fused epilogue =================
    if (tid < 64) { sImp[tid] = 0.f; sLoad[tid] = 0.f; }

    // per-head softmax (head w), write probs to P[row][w*64 + expert]
    const int qr = (lane >> 4) << 2;
#pragma unroll
    for (int mi = 0; mi < 2; ++mi) {
#pragma unroll
        for (int r = 0; r < 4; ++r) {
            float m = fmaxf(fmaxf(acc[mi][0][r], acc[mi][1][r]),
                            fmaxf(acc[mi][2][r], acc[mi][3][r]));
#pragma unroll
            for (int msk = 1; msk < 16; msk <<= 1)
                m = fmaxf(m, __shfl_xor(m, msk));
            float e[4], sa = 0.f;
#pragma unroll
            for (int ni = 0; ni < 4; ++ni) { e[ni] = __expf(acc[mi][ni][r] - m); sa += e[ni]; }
#pragma unroll
            for (int msk = 1; msk < 16; msk <<= 1)
                sa += __shfl_xor(sa, msk);
            float inv = 1.f / sa;
            int rl = mi * 16 + qr + r;
#pragma unroll
            for (int ni = 0; ni < 4; ++ni)
                P[rl * LDP + w * 64 + ni * 16 + (lane & 15)] = e[ni] * inv;
        }
    }
    __syncthreads();

    // consensus: wave w -> rows w*8..w*8+7; lane covers 8 experts of one row
    const int rl = (w << 3) + (lane >> 3);
    const int eb = (lane & 7) << 3;
    const float* Prow = P + rl * LDP;
    f32x4 pfa = (f32x4){0.f,0.f,0.f,0.f}, pfb = (f32x4){0.f,0.f,0.f,0.f};
#pragma unroll
    for (int gg = 0; gg < 4; ++gg) {
        pfa += *(const f32x4*)(Prow + gg * 64 + eb);
        pfb += *(const f32x4*)(Prow + gg * 64 + eb + 4);
    }
    pfa *= 0.25f; pfb *= 0.25f;

    const int rg = m0 + rl;
    *(f32x4*)(out + OUT_PF + (size_t)rg * 64 + eb)     = pfa;
    *(f32x4*)(out + OUT_PF + (size_t)rg * 64 + eb + 4) = pfb;

    // importance / load: reduce across the wave's 8 rows (masks 8,16,32)
    float ia[8], la[8];
#pragma unroll
    for (int j = 0; j < 4; ++j) {
        ia[j]     = pfa[j]; la[j]     = (pfa[j] > 0.f) ? 1.f : 0.f;
        ia[4 + j] = pfb[j]; la[4 + j] = (pfb[j] > 0.f) ? 1.f : 0.f;
    }
#pragma unroll
    for (int msk = 8; msk < 64; msk <<= 1)
#pragma unroll
        for (int j = 0; j < 8; ++j) {
            ia[j] += __shfl_xor(ia[j], msk);
            la[j] += __shfl_xor(la[j], msk);
        }
    if ((lane >> 3) == 0) {
#pragma unroll
        for (int j = 0; j < 8; ++j) {
            atomicAdd(&sImp[eb + j],  ia[j]);
            atomicAdd(&sLoad[eb + j], la[j]);
        }
    }

    // top-2 (jax tie-break: equal value -> lower index), local 8 then merge 8 lanes
    float v1 = -3.4e38f, v2 = -3.4e38f; int e1 = 0, e2 = 0;
#pragma unroll
    for (int j = 0; j < 8; ++j) {
        float val = (j < 4) ? pfa[j] : pfb[j - 4];
        int e = eb + j;
        if (val > v1) { v2 = v1; e2 = e1; v1 = val; e1 = e; }
        else if (val > v2) { v2 = val; e2 = e; }
    }
#pragma unroll
    for (int msk = 1; msk < 8; msk <<= 1) {
        float o1 = __shfl_xor(v1, msk); int oe1 = __shfl_xor(e1, msk);
        float o2 = __shfl_xor(v2, msk); int oe2 = __shfl_xor(e2, msk);
        bool ob = (o1 > v1) || (o1 == v1 && oe1 < e1);
        if (ob) {
            bool vb = (v1 > o2) || (v1 == o2 && e1 < oe2);
            v2 = vb ? v1 : o2; e2 = vb ? e1 : oe2;
            v1 = o1; e1 = oe1;
        } else {
            bool nb = (o1 > v2) || (o1 == v2 && oe1 < e2);
            v2 = nb ? o1 : v2; e2 = nb ? oe1 : e2;
        }
    }
    if ((lane & 7) == 0) {
        float den = fmaxf(v1 + v2, 1e-9f);
        out[(size_t)rg * 2]                  = (float)e1;
        out[(size_t)rg * 2 + 1]              = (float)e2;
        out[OUT_SCORES + (size_t)rg * 2]     = v1 / den;
        out[OUT_SCORES + (size_t)rg * 2 + 1] = v2 / den;
    }
    __syncthreads();
    if (tid < 64) {
        atomicAdd(out + OUT_IMP  + tid, sImp[tid]  * (1.0f / 16384.0f));
        atomicAdd(out + OUT_LOAD + tid, sLoad[tid] * (1.0f / 16384.0f));
    }
}

extern "C" void kernel_launch(void* const* d_in, const int* in_sizes, int n_in,
                              void* d_out, int out_size, void* d_ws, size_t ws_size,
                              hipStream_t stream) {
    const float* X = (const float*)d_in[0];
    const float* W = (const float*)d_in[1];
    float* out = (float*)d_out;
    char* ws = (char*)d_ws;

    _Float16* wfHi = (_Float16*)ws;
    _Float16* wfLo = (_Float16*)(ws + (2u << 20));

    // zero importance/load region of out (accumulated atomically by gemm_fused)
    hipMemsetAsync((void*)(out + OUT_IMP), 0, 128 * sizeof(float), stream);

    wprep<<<512, 256, 0, stream>>>(W, wfHi, wfLo);
    gemm_fused<<<512, 256, 0, stream>>>(X, wfHi, wfLo, out);
}